// Round 13
// baseline (277.582 us; speedup 1.0000x reference)
//
#include <hip/hip_runtime.h>
#include <math.h>

#define B_ 4
#define T_ 256
#define U_ 48
#define H_ 512
#define V_ 1024
#define BLANK_ (V_-1)

#define GM 1220        // B*T + B*(U+1)
#define GM_ENC 1024    // B*T
#define APAD 1280

#define INVLN2 1.4426950408889634f
#define LN2F   0.6931471805599453f

// measurement: amplify gemm1 only (idempotent reps; g1 = dispatch_dur / REP1)
#define REP1 16

typedef __attribute__((ext_vector_type(8))) short short8;
typedef __attribute__((ext_vector_type(4))) float f32x4;

__device__ __forceinline__ unsigned short f2bf(float x) {
    union { float f; unsigned int u; } c; c.f = x;
    unsigned int r = c.u + 0x7FFF + ((c.u >> 16) & 1);   // RNE
    return (unsigned short)(r >> 16);
}
__device__ __forceinline__ float bf2f(unsigned short u) {
    union { unsigned int i; float f; } c; c.i = ((unsigned int)u) << 16; return c.f;
}
__device__ __forceinline__ unsigned int cvt_pk_bf16(float lo, float hi) {
    unsigned int r;
    asm("v_cvt_pk_bf16_f32 %0, %1, %2" : "=v"(r) : "v"(lo), "v"(hi));
    return r;
}
// wave-wide shift-right-by-1 via DPP (pure VALU; lane0 <- fill)
__device__ __forceinline__ int wave_shr1_i(int x, int fill) {
    return __builtin_amdgcn_update_dpp(fill, x, 0x138 /*wave_shr:1*/, 0xf, 0xf, false);
}
__device__ __forceinline__ float wave_shr1_f(float x, float fill) {
    return __builtin_bit_cast(float,
        wave_shr1_i(__builtin_bit_cast(int, x), __builtin_bit_cast(int, fill)));
}

// ---------------- K1: Pexp = exp(([enc;dec]@W^T + bias)) bf16 — R9 structure x REP1
__global__ __launch_bounds__(512) void gemm1_kernel(
    const float* __restrict__ enc, const float* __restrict__ dec,
    const float* __restrict__ W, const float* __restrict__ bias,
    unsigned short* __restrict__ Pexp)
{
    __shared__ __attribute__((aligned(16))) unsigned short As[128 * 64];
    __shared__ __attribute__((aligned(16))) unsigned short Bs[128 * 64];
    const int tid  = threadIdx.x;
    const int lane = tid & 63, wave = tid >> 6;
    const int wm = wave >> 2, wn = wave & 3;        // 2 x 4 wave grid
    const int row0 = blockIdx.y * 128, col0 = blockIdx.x * 128;
    const int srow = tid >> 2;
    const int scg  = (tid & 3) * 16;

    for (int rep = 0; rep < REP1; ++rep) {
        f32x4 acc[4][2];
        #pragma unroll
        for (int mi = 0; mi < 4; ++mi)
            #pragma unroll
            for (int ni = 0; ni < 2; ++ni)
                acc[mi][ni] = (f32x4){0.f, 0.f, 0.f, 0.f};

        float4 ra[4], rb[4];
        auto loadAB = [&](int k0) {
            float4 z = make_float4(0.f, 0.f, 0.f, 0.f);
            ra[0] = ra[1] = ra[2] = ra[3] = z;
            int gr = row0 + srow;
            if (gr < GM) {
                const float* s = (gr < GM_ENC)
                    ? enc + (size_t)gr * H_ + k0 + scg
                    : dec + (size_t)(gr - GM_ENC) * H_ + k0 + scg;
                ra[0] = *(const float4*)s;       ra[1] = *(const float4*)(s + 4);
                ra[2] = *(const float4*)(s + 8); ra[3] = *(const float4*)(s + 12);
            }
            const float* s = W + (size_t)(col0 + srow) * H_ + k0 + scg;
            rb[0] = *(const float4*)s;       rb[1] = *(const float4*)(s + 4);
            rb[2] = *(const float4*)(s + 8); rb[3] = *(const float4*)(s + 12);
        };
        auto stage = [&]() {
            uint4 w0 = { cvt_pk_bf16(ra[0].x, ra[0].y), cvt_pk_bf16(ra[0].z, ra[0].w),
                         cvt_pk_bf16(ra[1].x, ra[1].y), cvt_pk_bf16(ra[1].z, ra[1].w) };
            uint4 w1 = { cvt_pk_bf16(ra[2].x, ra[2].y), cvt_pk_bf16(ra[2].z, ra[2].w),
                         cvt_pk_bf16(ra[3].x, ra[3].y), cvt_pk_bf16(ra[3].z, ra[3].w) };
            uint4 v0 = { cvt_pk_bf16(rb[0].x, rb[0].y), cvt_pk_bf16(rb[0].z, rb[0].w),
                         cvt_pk_bf16(rb[1].x, rb[1].y), cvt_pk_bf16(rb[1].z, rb[1].w) };
            uint4 v1 = { cvt_pk_bf16(rb[2].x, rb[2].y), cvt_pk_bf16(rb[2].z, rb[2].w),
                         cvt_pk_bf16(rb[3].x, rb[3].y), cvt_pk_bf16(rb[3].z, rb[3].w) };
            int colb = scg * 2;
            int sw0 = (colb)      ^ ((srow & 7) << 4);
            int sw1 = (colb + 16) ^ ((srow & 7) << 4);
            *(uint4*)((char*)As + srow * 128 + sw0) = w0;
            *(uint4*)((char*)As + srow * 128 + sw1) = w1;
            *(uint4*)((char*)Bs + srow * 128 + sw0) = v0;
            *(uint4*)((char*)Bs + srow * 128 + sw1) = v1;
        };
        auto compute = [&]() {
            #pragma unroll
            for (int kk = 0; kk < 2; ++kk) {
                short8 a[4], bfr[2];
                const int cb = kk * 64 + (lane >> 4) * 16;
                #pragma unroll
                for (int mi = 0; mi < 4; ++mi) {
                    int r = wm * 64 + mi * 16 + (lane & 15);
                    a[mi] = *(const short8*)((const char*)As + r * 128 + (cb ^ ((r & 7) << 4)));
                }
                #pragma unroll
                for (int ni = 0; ni < 2; ++ni) {
                    int r = wn * 32 + ni * 16 + (lane & 15);
                    bfr[ni] = *(const short8*)((const char*)Bs + r * 128 + (cb ^ ((r & 7) << 4)));
                }
                #pragma unroll
                for (int mi = 0; mi < 4; ++mi)
                    #pragma unroll
                    for (int ni = 0; ni < 2; ++ni)
                        asm("v_mfma_f32_16x16x32_bf16 %0, %1, %2, %0"
                            : "+v"(acc[mi][ni]) : "v"(a[mi]), "v"(bfr[ni]));
            }
        };

        loadAB(0);
        for (int k0 = 0; k0 < H_; k0 += 64) {
            stage();
            asm volatile("s_waitcnt lgkmcnt(0)" ::: "memory");
            __builtin_amdgcn_s_barrier();
            asm volatile("" ::: "memory");
            if (k0 + 64 < H_) loadAB(k0 + 64);
            compute();
            asm volatile("" ::: "memory");
            __builtin_amdgcn_s_barrier();
            asm volatile("" ::: "memory");
        }

        #pragma unroll
        for (int ni = 0; ni < 2; ++ni) {
            int col = col0 + wn * 32 + ni * 16 + (lane & 15);
            float bb = bias[col];
            #pragma unroll
            for (int mi = 0; mi < 4; ++mi) {
                #pragma unroll
                for (int j = 0; j < 4; ++j) {
                    int gr = row0 + wm * 64 + mi * 16 + (lane >> 4) * 4 + j;
                    if (gr >= GM) continue;
                    float v = acc[mi][ni][j] + (gr < GM_ENC ? bb : 0.f);
                    Pexp[(size_t)gr * V_ + col] = f2bf(__builtin_amdgcn_exp2f(v * INVLN2));
                }
            }
        }
        asm volatile("" ::: "memory");
    }
}

// ---------------- K2: denom GEMM + linear fp32 pb/pl epilogue (R12, unchanged)
__global__ __launch_bounds__(256) void gemm2_kernel(
    const unsigned short* __restrict__ Pexp, const int* __restrict__ targets,
    float* __restrict__ lp)
{
    __shared__ __attribute__((aligned(16))) unsigned short As[64 * 64];
    __shared__ __attribute__((aligned(16))) unsigned short Bs[64 * 64];
    __shared__ float eb[64];
    __shared__ float db[64];
    __shared__ float dg[64];
    __shared__ int   tgts[64];
    const int tid  = threadIdx.x;
    const int lane = tid & 63, wave = tid >> 6;
    const int wm = wave >> 1, wn = wave & 1;
    const int mt = blockIdx.x, b = blockIdx.y;

    if (tid < 64) {
        eb[tid] = bf2f(Pexp[(size_t)(b * 256 + mt * 64 + tid) * V_ + BLANK_]);
    } else if (tid < 128) {
        int u = tid - 64;
        if (u <= U_) {
            size_t drow = (size_t)(GM_ENC + b * (U_ + 1) + u);
            db[u] = bf2f(Pexp[drow * V_ + BLANK_]);
            if (u < U_) {
                int tg = targets[b * U_ + u];
                tgts[u] = tg;
                dg[u] = bf2f(Pexp[drow * V_ + tg]);
            }
        }
    }

    f32x4 acc[2][2];
    #pragma unroll
    for (int mi = 0; mi < 2; ++mi)
        #pragma unroll
        for (int ni = 0; ni < 2; ++ni)
            acc[mi][ni] = (f32x4){0.f, 0.f, 0.f, 0.f};

    short8 a2[2], b2[2];
    auto loadT = [&](int k0) {
        #pragma unroll
        for (int c = 0; c < 2; ++c) {
            int off = (tid + 256 * c) * 16;
            int row = off >> 7, colb = off & 127;
            size_t arow = (size_t)(b * 256 + mt * 64 + row);
            a2[c] = *(const short8*)((const char*)Pexp + arow * (V_*2) + k0*2 + colb);
            size_t brow = (size_t)(GM_ENC + b * (U_ + 1) + (row <= U_ ? row : U_));
            b2[c] = *(const short8*)((const char*)Pexp + brow * (V_*2) + k0*2 + colb);
        }
    };
    auto stageT = [&]() {
        #pragma unroll
        for (int c = 0; c < 2; ++c) {
            int off = (tid + 256 * c) * 16;
            int row = off >> 7, colb = off & 127;
            int sw = colb ^ ((row & 7) << 4);
            *(short8*)((char*)As + row * 128 + sw) = a2[c];
            *(short8*)((char*)Bs + row * 128 + sw) = b2[c];
        }
    };

    loadT(0);
    for (int k0 = 0; k0 < V_; k0 += 64) {
        stageT();
        asm volatile("s_waitcnt lgkmcnt(0)" ::: "memory");
        __builtin_amdgcn_s_barrier();
        asm volatile("" ::: "memory");
        if (k0 + 64 < V_) loadT(k0 + 64);
        #pragma unroll
        for (int kk = 0; kk < 2; ++kk) {
            short8 a[2], bfr[2];
            const int cb = kk * 64 + (lane >> 4) * 16;
            #pragma unroll
            for (int mi = 0; mi < 2; ++mi) {
                int r = wm * 32 + mi * 16 + (lane & 15);
                a[mi] = *(const short8*)((const char*)As + r * 128 + (cb ^ ((r & 7) << 4)));
            }
            #pragma unroll
            for (int ni = 0; ni < 2; ++ni) {
                int r = wn * 32 + ni * 16 + (lane & 15);
                bfr[ni] = *(const short8*)((const char*)Bs + r * 128 + (cb ^ ((r & 7) << 4)));
            }
            #pragma unroll
            for (int mi = 0; mi < 2; ++mi)
                #pragma unroll
                for (int ni = 0; ni < 2; ++ni)
                    asm("v_mfma_f32_16x16x32_bf16 %0, %1, %2, %0"
                        : "+v"(acc[mi][ni]) : "v"(a[mi]), "v"(bfr[ni]));
        }
        asm volatile("" ::: "memory");
        __builtin_amdgcn_s_barrier();
        asm volatile("" ::: "memory");
    }

    // linear epilogue: pb = eb*db/denom ; pl = eg*dg/denom
    #pragma unroll
    for (int ni = 0; ni < 2; ++ni) {
        int u = wn * 32 + ni * 16 + (lane & 15);
        if (u > U_) continue;
        float dbu = db[u];
        float dgu = (u < U_) ? dg[u] : 0.f;
        int   tgu = (u < U_) ? tgts[u] : 0;
        #pragma unroll
        for (int mi = 0; mi < 2; ++mi) {
            #pragma unroll
            for (int j = 0; j < 4; ++j) {
                int tp = wm * 32 + mi * 16 + (lane >> 4) * 4 + j;
                int t  = mt * 64 + tp;
                float rd = __builtin_amdgcn_rcpf(acc[mi][ni][j]);
                lp[((size_t)b * 97 + u) * T_ + t] = eb[tp] * dbu * rd;
                if (u < U_) {
                    float eg = bf2f(Pexp[(size_t)(b * 256 + t) * V_ + tgu]);
                    lp[((size_t)b * 97 + 49 + u) * T_ + t] = eg * dgu * rd;
                }
            }
        }
    }
}

// ---------------- K3: RNN-T alpha DP — f32 scaled linear (R12 math), LDS row
// stride 257 floats: payload bank = (s+3l+j)%32, 2 lanes/bank = conflict-free.
__global__ __launch_bounds__(256) void dp_kernel(
    const float* __restrict__ lp,
    const int* __restrict__ tlen, const int* __restrict__ ulen,
    float* __restrict__ out)
{
    __shared__ __attribute__((aligned(16))) float sm[97 * 257 + 3];  // stride-257 rows
    const int b = blockIdx.x;
    const int tid = threadIdx.x;
    {
        const float4* g = (const float4*)(lp + (size_t)b * 97 * T_);
        for (int i = tid; i < 97 * T_ / 4; i += 256) {
            float4 v = g[i];
            int r = i >> 6;            // row (64 float4 per row)
            int t = (i & 63) << 2;     // col
            float* d = sm + r * 257 + t;
            d[0] = v.x; d[1] = v.y; d[2] = v.z; d[3] = v.w;
        }
    }
    __syncthreads();
    if (tid >= 64) return;

    const int l = tid;
    const int TL = tlen[b], UL = ulen[b];
    const int lt = (TL - 1) >> 2;
    const int smax = lt + UL;

    const int ROWB = 257 * 4;                       // 1028 B row stride
    const int bLo = 16 * l, bHi = 48 * ROWB + 16 * l;
    const int lLo = 49 * ROWB + 16 * l, lHi = 96 * ROWB + 16 * l;
    int wb = -l * ROWB + 16 * l;

    float M0 = 0.f, M1 = 0.f, M2 = 0.f, M3 = 0.f;
    int E = 0;
    float wprev = 0.f;

    struct Pay { float b0, b1, b2, b3, l0, l1, l2, l3; };
    Pay pA, pB;
    auto issue = [&](Pay& P) {
        int ab = min(max(wb, bLo), bHi);
        int al = min(max(wb + 48 * ROWB, lLo), lHi);
        const char* base = (const char*)sm;
        P.b0 = *(const float*)(base + ab);
        P.b1 = *(const float*)(base + ab + 4);
        P.b2 = *(const float*)(base + ab + 8);
        P.b3 = *(const float*)(base + ab + 12);
        P.l0 = *(const float*)(base + al);
        P.l1 = *(const float*)(base + al + 4);
        P.l2 = *(const float*)(base + al + 8);
        P.l3 = *(const float*)(base + al + 12);
        wb += ROWB;
    };
    auto step = [&](int s, const Pay& P) {
        float bm  = wave_shr1_f(M3, 0.f);
        int   bE  = wave_shr1_i(E, -(1 << 24));
        float B0f = wave_shr1_f(wprev, 0.f);
        wprev = P.b3;
        int u = s - l;
        if (u >= 0 && u <= U_) {
            bool act  = (u == 0);
            bool seed = (s == 0);
            int Eu = act ? bE : max(E, bE);
            if (seed) Eu = 0;
            float sb = ldexpf(bm, bE - Eu);              // shift <= 0
            float sO = act ? 0.f : ldexpf(1.0f, E - Eu); // shift <= 0
            float m0 = M0 * sO, m1 = M1 * sO, m2 = M2 * sO, m3 = M3 * sO;
            float A0 = fmaf(sb, B0f, m0 * P.l0);
            if (seed) A0 = 1.0f;                         // alpha[0][0] = 1
            float A1 = fmaf(A0, P.b0, m1 * P.l1);
            float A2 = fmaf(A1, P.b1, m2 * P.l2);
            float A3 = fmaf(A2, P.b2, m3 * P.l3);
            float mx = fmaxf(fmaxf(A0, A1), fmaxf(A2, A3));
            int e = (int)((__builtin_bit_cast(unsigned, mx) >> 23) & 0xFF) - 126;
            M0 = ldexpf(A0, -e); M1 = ldexpf(A1, -e);
            M2 = ldexpf(A2, -e); M3 = ldexpf(A3, -e);
            E = Eu + e;
        }
    };

    issue(pA);
    issue(pB);
    int s = 0;
    for (; s + 1 <= smax; s += 2) {
        step(s, pA);     issue(pA);
        step(s + 1, pB); issue(pB);
    }
    if (s <= smax) step(s, pA);

    if (l == lt) {
        int j = (TL - 1) & 3;
        float rm = (j == 0) ? M0 : (j == 1) ? M1 : (j == 2) ? M2 : M3;
        float lfin = __builtin_amdgcn_logf(rm) + (float)E
                   + __builtin_amdgcn_logf(sm[UL * 257 + (TL - 1)]);
        out[b] = -lfin * LN2F;
    }
}

extern "C" void kernel_launch(void* const* d_in, const int* in_sizes, int n_in,
                              void* d_out, int out_size, void* d_ws, size_t ws_size,
                              hipStream_t stream) {
    const float* enc     = (const float*)d_in[0];
    const float* dec     = (const float*)d_in[1];
    const float* W       = (const float*)d_in[2];
    const float* bias    = (const float*)d_in[3];
    const int*   targets = (const int*)d_in[4];
    const int*   tlen    = (const int*)d_in[5];
    const int*   ulen    = (const int*)d_in[6];
    float* out = (float*)d_out;

    unsigned short* Pexp = (unsigned short*)d_ws;       // APAD x V bf16
    float* lp = (float*)(Pexp + (size_t)APAD * V_);     // [B][97][T] linear fp32 probs

    gemm1_kernel<<<dim3(V_/128, APAD/128), dim3(512), 0, stream>>>(
        enc, dec, W, bias, Pexp);

    gemm2_kernel<<<dim3(4, B_), dim3(256), 0, stream>>>(Pexp, targets, lp);

    dp_kernel<<<dim3(B_), dim3(256), 0, stream>>>(lp, tlen, ulen, out);
}

// Round 14
// 45.612 us; speedup vs baseline: 6.0858x; 6.0858x over previous
//
#include <hip/hip_runtime.h>
#include <math.h>

#define B_ 4
#define T_ 256
#define U_ 48
#define H_ 512
#define V_ 1024
#define BLANK_ (V_-1)

#define GM 1220        // B*T + B*(U+1)
#define GM_ENC 1024    // B*T
#define APAD 1280

#define INVLN2 1.4426950408889634f
#define LN2F   0.6931471805599453f

typedef __attribute__((ext_vector_type(8))) short short8;
typedef __attribute__((ext_vector_type(4))) float f32x4;

__device__ __forceinline__ unsigned short f2bf(float x) {
    union { float f; unsigned int u; } c; c.f = x;
    unsigned int r = c.u + 0x7FFF + ((c.u >> 16) & 1);   // RNE
    return (unsigned short)(r >> 16);
}
__device__ __forceinline__ float bf2f(unsigned short u) {
    union { unsigned int i; float f; } c; c.i = ((unsigned int)u) << 16; return c.f;
}
__device__ __forceinline__ unsigned int cvt_pk_bf16(float lo, float hi) {
    unsigned int r;
    asm("v_cvt_pk_bf16_f32 %0, %1, %2" : "=v"(r) : "v"(lo), "v"(hi));
    return r;
}
// wave-wide shift-right-by-1 via DPP (pure VALU; lane0 <- fill)
__device__ __forceinline__ int wave_shr1_i(int x, int fill) {
    return __builtin_amdgcn_update_dpp(fill, x, 0x138 /*wave_shr:1*/, 0xf, 0xf, false);
}
__device__ __forceinline__ float wave_shr1_f(float x, float fill) {
    return __builtin_bit_cast(float,
        wave_shr1_i(__builtin_bit_cast(int, x), __builtin_bit_cast(int, fill)));
}

// ---------------- K1: Pexp = exp(([enc;dec]@W^T + bias)) bf16.
// 64x64 tiles -> grid (16,20)=320 blocks (full chip), 256 thr / 4 waves (2x2),
// BK=64, 16 KB LDS, reg-prefetch pipeline (loads in flight across barriers).
__global__ __launch_bounds__(256) void gemm1_kernel(
    const float* __restrict__ enc, const float* __restrict__ dec,
    const float* __restrict__ W, const float* __restrict__ bias,
    unsigned short* __restrict__ Pexp)
{
    __shared__ __attribute__((aligned(16))) unsigned short As[64 * 64];  // 8 KB
    __shared__ __attribute__((aligned(16))) unsigned short Bs[64 * 64];  // 8 KB
    const int tid  = threadIdx.x;
    const int lane = tid & 63, wave = tid >> 6;
    const int wm = wave >> 1, wn = wave & 1;        // 2x2 wave grid, 32x32 each
    const int row0 = blockIdx.y * 64, col0 = blockIdx.x * 64;
    const int srow = tid >> 2;                      // staging row 0..63
    const int scg  = (tid & 3) * 16;                // fp32 col group (16 elems)

    f32x4 acc[2][2];
    #pragma unroll
    for (int mi = 0; mi < 2; ++mi)
        #pragma unroll
        for (int ni = 0; ni < 2; ++ni)
            acc[mi][ni] = (f32x4){0.f, 0.f, 0.f, 0.f};

    const int gr = row0 + srow;
    const float* srcA = (gr < GM_ENC) ? enc + (size_t)gr * H_
                      : (gr < GM)     ? dec + (size_t)(gr - GM_ENC) * H_
                                      : (const float*)0;
    const float* srcB = W + (size_t)(col0 + srow) * H_;

    float4 ra[4], rb[4];
    auto loadAB = [&](int k0) {
        float4 z = make_float4(0.f, 0.f, 0.f, 0.f);
        ra[0] = ra[1] = ra[2] = ra[3] = z;
        if (srcA) {
            const float* s = srcA + k0 + scg;
            ra[0] = *(const float4*)s;       ra[1] = *(const float4*)(s + 4);
            ra[2] = *(const float4*)(s + 8); ra[3] = *(const float4*)(s + 12);
        }
        const float* s = srcB + k0 + scg;
        rb[0] = *(const float4*)s;       rb[1] = *(const float4*)(s + 4);
        rb[2] = *(const float4*)(s + 8); rb[3] = *(const float4*)(s + 12);
    };
    auto stage = [&]() {
        uint4 w0 = { cvt_pk_bf16(ra[0].x, ra[0].y), cvt_pk_bf16(ra[0].z, ra[0].w),
                     cvt_pk_bf16(ra[1].x, ra[1].y), cvt_pk_bf16(ra[1].z, ra[1].w) };
        uint4 w1 = { cvt_pk_bf16(ra[2].x, ra[2].y), cvt_pk_bf16(ra[2].z, ra[2].w),
                     cvt_pk_bf16(ra[3].x, ra[3].y), cvt_pk_bf16(ra[3].z, ra[3].w) };
        uint4 v0 = { cvt_pk_bf16(rb[0].x, rb[0].y), cvt_pk_bf16(rb[0].z, rb[0].w),
                     cvt_pk_bf16(rb[1].x, rb[1].y), cvt_pk_bf16(rb[1].z, rb[1].w) };
        uint4 v1 = { cvt_pk_bf16(rb[2].x, rb[2].y), cvt_pk_bf16(rb[2].z, rb[2].w),
                     cvt_pk_bf16(rb[3].x, rb[3].y), cvt_pk_bf16(rb[3].z, rb[3].w) };
        int colb = scg * 2;                       // byte col within 128 B row
        int sw0 = (colb)      ^ ((srow & 7) << 4);
        int sw1 = (colb + 16) ^ ((srow & 7) << 4);
        *(uint4*)((char*)As + srow * 128 + sw0) = w0;
        *(uint4*)((char*)As + srow * 128 + sw1) = w1;
        *(uint4*)((char*)Bs + srow * 128 + sw0) = v0;
        *(uint4*)((char*)Bs + srow * 128 + sw1) = v1;
    };
    auto compute = [&]() {
        #pragma unroll
        for (int kk = 0; kk < 2; ++kk) {
            short8 a[2], b[2];
            const int cb = kk * 64 + (lane >> 4) * 16;
            #pragma unroll
            for (int mi = 0; mi < 2; ++mi) {
                int r = wm * 32 + mi * 16 + (lane & 15);
                a[mi] = *(const short8*)((const char*)As + r * 128 + (cb ^ ((r & 7) << 4)));
            }
            #pragma unroll
            for (int ni = 0; ni < 2; ++ni) {
                int r = wn * 32 + ni * 16 + (lane & 15);
                b[ni] = *(const short8*)((const char*)Bs + r * 128 + (cb ^ ((r & 7) << 4)));
            }
            #pragma unroll
            for (int mi = 0; mi < 2; ++mi)
                #pragma unroll
                for (int ni = 0; ni < 2; ++ni)
                    asm("v_mfma_f32_16x16x32_bf16 %0, %1, %2, %0"
                        : "+v"(acc[mi][ni]) : "v"(a[mi]), "v"(b[ni]));
        }
    };

    loadAB(0);
    for (int k0 = 0; k0 < H_; k0 += 64) {
        stage();
        asm volatile("s_waitcnt lgkmcnt(0)" ::: "memory");
        __builtin_amdgcn_s_barrier();
        asm volatile("" ::: "memory");
        if (k0 + 64 < H_) loadAB(k0 + 64);     // prefetch in flight across barrier
        compute();
        asm volatile("" ::: "memory");
        __builtin_amdgcn_s_barrier();
        asm volatile("" ::: "memory");
    }

    // epilogue: C/D layout col=lane&15, row=(lane>>4)*4+j
    #pragma unroll
    for (int ni = 0; ni < 2; ++ni) {
        int col = col0 + wn * 32 + ni * 16 + (lane & 15);
        float bb = bias[col];
        #pragma unroll
        for (int mi = 0; mi < 2; ++mi) {
            #pragma unroll
            for (int j = 0; j < 4; ++j) {
                int r = row0 + wm * 32 + mi * 16 + (lane >> 4) * 4 + j;
                if (r >= GM) continue;
                float v = acc[mi][ni][j] + (r < GM_ENC ? bb : 0.f);
                Pexp[(size_t)r * V_ + col] = f2bf(__builtin_amdgcn_exp2f(v * INVLN2));
            }
        }
    }
}

// ---------------- K2: denom GEMM + linear fp32 pb/pl epilogue (R13, unchanged)
__global__ __launch_bounds__(256) void gemm2_kernel(
    const unsigned short* __restrict__ Pexp, const int* __restrict__ targets,
    float* __restrict__ lp)
{
    __shared__ __attribute__((aligned(16))) unsigned short As[64 * 64];
    __shared__ __attribute__((aligned(16))) unsigned short Bs[64 * 64];
    __shared__ float eb[64];
    __shared__ float db[64];
    __shared__ float dg[64];
    __shared__ int   tgts[64];
    const int tid  = threadIdx.x;
    const int lane = tid & 63, wave = tid >> 6;
    const int wm = wave >> 1, wn = wave & 1;
    const int mt = blockIdx.x, b = blockIdx.y;

    if (tid < 64) {
        eb[tid] = bf2f(Pexp[(size_t)(b * 256 + mt * 64 + tid) * V_ + BLANK_]);
    } else if (tid < 128) {
        int u = tid - 64;
        if (u <= U_) {
            size_t drow = (size_t)(GM_ENC + b * (U_ + 1) + u);
            db[u] = bf2f(Pexp[drow * V_ + BLANK_]);
            if (u < U_) {
                int tg = targets[b * U_ + u];
                tgts[u] = tg;
                dg[u] = bf2f(Pexp[drow * V_ + tg]);
            }
        }
    }

    f32x4 acc[2][2];
    #pragma unroll
    for (int mi = 0; mi < 2; ++mi)
        #pragma unroll
        for (int ni = 0; ni < 2; ++ni)
            acc[mi][ni] = (f32x4){0.f, 0.f, 0.f, 0.f};

    short8 a2[2], b2[2];
    auto loadT = [&](int k0) {
        #pragma unroll
        for (int c = 0; c < 2; ++c) {
            int off = (tid + 256 * c) * 16;
            int row = off >> 7, colb = off & 127;
            size_t arow = (size_t)(b * 256 + mt * 64 + row);
            a2[c] = *(const short8*)((const char*)Pexp + arow * (V_*2) + k0*2 + colb);
            size_t brow = (size_t)(GM_ENC + b * (U_ + 1) + (row <= U_ ? row : U_));
            b2[c] = *(const short8*)((const char*)Pexp + brow * (V_*2) + k0*2 + colb);
        }
    };
    auto stageT = [&]() {
        #pragma unroll
        for (int c = 0; c < 2; ++c) {
            int off = (tid + 256 * c) * 16;
            int row = off >> 7, colb = off & 127;
            int sw = colb ^ ((row & 7) << 4);
            *(short8*)((char*)As + row * 128 + sw) = a2[c];
            *(short8*)((char*)Bs + row * 128 + sw) = b2[c];
        }
    };

    loadT(0);
    for (int k0 = 0; k0 < V_; k0 += 64) {
        stageT();
        asm volatile("s_waitcnt lgkmcnt(0)" ::: "memory");
        __builtin_amdgcn_s_barrier();
        asm volatile("" ::: "memory");
        if (k0 + 64 < V_) loadT(k0 + 64);
        #pragma unroll
        for (int kk = 0; kk < 2; ++kk) {
            short8 a[2], bfr[2];
            const int cb = kk * 64 + (lane >> 4) * 16;
            #pragma unroll
            for (int mi = 0; mi < 2; ++mi) {
                int r = wm * 32 + mi * 16 + (lane & 15);
                a[mi] = *(const short8*)((const char*)As + r * 128 + (cb ^ ((r & 7) << 4)));
            }
            #pragma unroll
            for (int ni = 0; ni < 2; ++ni) {
                int r = wn * 32 + ni * 16 + (lane & 15);
                bfr[ni] = *(const short8*)((const char*)Bs + r * 128 + (cb ^ ((r & 7) << 4)));
            }
            #pragma unroll
            for (int mi = 0; mi < 2; ++mi)
                #pragma unroll
                for (int ni = 0; ni < 2; ++ni)
                    asm("v_mfma_f32_16x16x32_bf16 %0, %1, %2, %0"
                        : "+v"(acc[mi][ni]) : "v"(a[mi]), "v"(bfr[ni]));
        }
        asm volatile("" ::: "memory");
        __builtin_amdgcn_s_barrier();
        asm volatile("" ::: "memory");
    }

    // linear epilogue: pb = eb*db/denom ; pl = eg*dg/denom
    #pragma unroll
    for (int ni = 0; ni < 2; ++ni) {
        int u = wn * 32 + ni * 16 + (lane & 15);
        if (u > U_) continue;
        float dbu = db[u];
        float dgu = (u < U_) ? dg[u] : 0.f;
        int   tgu = (u < U_) ? tgts[u] : 0;
        #pragma unroll
        for (int mi = 0; mi < 2; ++mi) {
            #pragma unroll
            for (int j = 0; j < 4; ++j) {
                int tp = wm * 32 + mi * 16 + (lane >> 4) * 4 + j;
                int t  = mt * 64 + tp;
                float rd = __builtin_amdgcn_rcpf(acc[mi][ni][j]);
                lp[((size_t)b * 97 + u) * T_ + t] = eb[tp] * dbu * rd;
                if (u < U_) {
                    float eg = bf2f(Pexp[(size_t)(b * 256 + t) * V_ + tgu]);
                    lp[((size_t)b * 97 + 49 + u) * T_ + t] = eg * dgu * rd;
                }
            }
        }
    }
}

// ---------------- K3: RNN-T alpha DP — f32 scaled linear, stride-257 LDS (R13, unchanged)
__global__ __launch_bounds__(256) void dp_kernel(
    const float* __restrict__ lp,
    const int* __restrict__ tlen, const int* __restrict__ ulen,
    float* __restrict__ out)
{
    __shared__ __attribute__((aligned(16))) float sm[97 * 257 + 3];  // stride-257 rows
    const int b = blockIdx.x;
    const int tid = threadIdx.x;
    {
        const float4* g = (const float4*)(lp + (size_t)b * 97 * T_);
        for (int i = tid; i < 97 * T_ / 4; i += 256) {
            float4 v = g[i];
            int r = i >> 6;            // row (64 float4 per row)
            int t = (i & 63) << 2;     // col
            float* d = sm + r * 257 + t;
            d[0] = v.x; d[1] = v.y; d[2] = v.z; d[3] = v.w;
        }
    }
    __syncthreads();
    if (tid >= 64) return;

    const int l = tid;
    const int TL = tlen[b], UL = ulen[b];
    const int lt = (TL - 1) >> 2;
    const int smax = lt + UL;

    const int ROWB = 257 * 4;                       // 1028 B row stride
    const int bLo = 16 * l, bHi = 48 * ROWB + 16 * l;
    const int lLo = 49 * ROWB + 16 * l, lHi = 96 * ROWB + 16 * l;
    int wb = -l * ROWB + 16 * l;

    float M0 = 0.f, M1 = 0.f, M2 = 0.f, M3 = 0.f;
    int E = 0;
    float wprev = 0.f;

    struct Pay { float b0, b1, b2, b3, l0, l1, l2, l3; };
    Pay pA, pB;
    auto issue = [&](Pay& P) {
        int ab = min(max(wb, bLo), bHi);
        int al = min(max(wb + 48 * ROWB, lLo), lHi);
        const char* base = (const char*)sm;
        P.b0 = *(const float*)(base + ab);
        P.b1 = *(const float*)(base + ab + 4);
        P.b2 = *(const float*)(base + ab + 8);
        P.b3 = *(const float*)(base + ab + 12);
        P.l0 = *(const float*)(base + al);
        P.l1 = *(const float*)(base + al + 4);
        P.l2 = *(const float*)(base + al + 8);
        P.l3 = *(const float*)(base + al + 12);
        wb += ROWB;
    };
    auto step = [&](int s, const Pay& P) {
        float bm  = wave_shr1_f(M3, 0.f);
        int   bE  = wave_shr1_i(E, -(1 << 24));
        float B0f = wave_shr1_f(wprev, 0.f);
        wprev = P.b3;
        int u = s - l;
        if (u >= 0 && u <= U_) {
            bool act  = (u == 0);
            bool seed = (s == 0);
            int Eu = act ? bE : max(E, bE);
            if (seed) Eu = 0;
            float sb = ldexpf(bm, bE - Eu);              // shift <= 0
            float sO = act ? 0.f : ldexpf(1.0f, E - Eu); // shift <= 0
            float m0 = M0 * sO, m1 = M1 * sO, m2 = M2 * sO, m3 = M3 * sO;
            float A0 = fmaf(sb, B0f, m0 * P.l0);
            if (seed) A0 = 1.0f;                         // alpha[0][0] = 1
            float A1 = fmaf(A0, P.b0, m1 * P.l1);
            float A2 = fmaf(A1, P.b1, m2 * P.l2);
            float A3 = fmaf(A2, P.b2, m3 * P.l3);
            float mx = fmaxf(fmaxf(A0, A1), fmaxf(A2, A3));
            int e = (int)((__builtin_bit_cast(unsigned, mx) >> 23) & 0xFF) - 126;
            M0 = ldexpf(A0, -e); M1 = ldexpf(A1, -e);
            M2 = ldexpf(A2, -e); M3 = ldexpf(A3, -e);
            E = Eu + e;
        }
    };

    issue(pA);
    issue(pB);
    int s = 0;
    for (; s + 1 <= smax; s += 2) {
        step(s, pA);     issue(pA);
        step(s + 1, pB); issue(pB);
    }
    if (s <= smax) step(s, pA);

    if (l == lt) {
        int j = (TL - 1) & 3;
        float rm = (j == 0) ? M0 : (j == 1) ? M1 : (j == 2) ? M2 : M3;
        float lfin = __builtin_amdgcn_logf(rm) + (float)E
                   + __builtin_amdgcn_logf(sm[UL * 257 + (TL - 1)]);
        out[b] = -lfin * LN2F;
    }
}

extern "C" void kernel_launch(void* const* d_in, const int* in_sizes, int n_in,
                              void* d_out, int out_size, void* d_ws, size_t ws_size,
                              hipStream_t stream) {
    const float* enc     = (const float*)d_in[0];
    const float* dec     = (const float*)d_in[1];
    const float* W       = (const float*)d_in[2];
    const float* bias    = (const float*)d_in[3];
    const int*   targets = (const int*)d_in[4];
    const int*   tlen    = (const int*)d_in[5];
    const int*   ulen    = (const int*)d_in[6];
    float* out = (float*)d_out;

    unsigned short* Pexp = (unsigned short*)d_ws;       // APAD x V bf16
    float* lp = (float*)(Pexp + (size_t)APAD * V_);     // [B][97][T] linear fp32 probs

    gemm1_kernel<<<dim3(V_/64, APAD/64), dim3(256), 0, stream>>>(
        enc, dec, W, bias, Pexp);

    gemm2_kernel<<<dim3(4, B_), dim3(256), 0, stream>>>(Pexp, targets, lp);

    dp_kernel<<<dim3(B_), dim3(256), 0, stream>>>(lp, tlen, ulen, out);
}